// Round 1
// baseline (313.631 us; speedup 1.0000x reference)
//
#include <hip/hip_runtime.h>
#include <math.h>

// Problem constants
#define Bb   2
#define Hh   64
#define Ww   160
#define DIMc 256
#define NHh  8
#define HDd  32
#define Nn   (Hh * Ww)          // 10240 positions per batch
#define Aa   16                 // window size 4x4
#define SCALEf 0.17677669529663687f  // 32^-0.5

// ---------------------------------------------------------------------------
// Tiled fp32 GEMM: C[M x 256] = A[M x 256] @ B[256 x 256]
// 64x64 tile per block, 256 threads, 4x4 microtile per thread, BK=16.
// ---------------------------------------------------------------------------
__device__ __forceinline__ void gemm_tile(const float* __restrict__ Ag,
                                          const float* __restrict__ Bg,
                                          float* __restrict__ Cg)
{
    __shared__ float sA[16][65];   // +1 pad: avoids 4-way bank conflict on transpose-store
    __shared__ float sB[16][64];

    const int t  = threadIdx.x;
    const int m0 = blockIdx.y * 64;
    const int n0 = blockIdx.x * 64;
    const int tx = t & 15;         // column group
    const int ty = t >> 4;         // row group

    // A-tile load mapping: 64 rows x 16 k, float4 per thread
    const int la_m  = t >> 2;          // 0..63
    const int la_k  = (t & 3) * 4;     // 0,4,8,12
    // B-tile load mapping: 16 k-rows x 64 n, float4 per thread
    const int lb_k  = t >> 4;          // 0..15
    const int lb_n  = (t & 15) * 4;    // 0..60

    float acc[4][4] = {};

    for (int k0 = 0; k0 < 256; k0 += 16) {
        float4 av = *(const float4*)&Ag[(size_t)(m0 + la_m) * 256 + k0 + la_k];
        float4 bv = *(const float4*)&Bg[(size_t)(k0 + lb_k) * 256 + n0 + lb_n];
        __syncthreads();
        sA[la_k + 0][la_m] = av.x;
        sA[la_k + 1][la_m] = av.y;
        sA[la_k + 2][la_m] = av.z;
        sA[la_k + 3][la_m] = av.w;
        *(float4*)&sB[lb_k][lb_n] = bv;
        __syncthreads();

#pragma unroll
        for (int kk = 0; kk < 16; ++kk) {
            float a0 = sA[kk][ty * 4 + 0];
            float a1 = sA[kk][ty * 4 + 1];
            float a2 = sA[kk][ty * 4 + 2];
            float a3 = sA[kk][ty * 4 + 3];
            float b0 = sB[kk][tx * 4 + 0];
            float b1 = sB[kk][tx * 4 + 1];
            float b2 = sB[kk][tx * 4 + 2];
            float b3 = sB[kk][tx * 4 + 3];
            acc[0][0] += a0 * b0; acc[0][1] += a0 * b1; acc[0][2] += a0 * b2; acc[0][3] += a0 * b3;
            acc[1][0] += a1 * b0; acc[1][1] += a1 * b1; acc[1][2] += a1 * b2; acc[1][3] += a1 * b3;
            acc[2][0] += a2 * b0; acc[2][1] += a2 * b1; acc[2][2] += a2 * b2; acc[2][3] += a2 * b3;
            acc[3][0] += a3 * b0; acc[3][1] += a3 * b1; acc[3][2] += a3 * b2; acc[3][3] += a3 * b3;
        }
    }

#pragma unroll
    for (int i = 0; i < 4; ++i) {
        float4 cv = make_float4(acc[i][0], acc[i][1], acc[i][2], acc[i][3]);
        *(float4*)&Cg[(size_t)(m0 + ty * 4 + i) * 256 + n0 + tx * 4] = cv;
    }
}

// Fused QKV: grid.z in {0,1,2} selects which weight / output
__global__ __launch_bounds__(256) void gemm_qkv(const float* __restrict__ X,
                                                const float* __restrict__ Wq,
                                                const float* __restrict__ Wk,
                                                const float* __restrict__ Wv,
                                                float* __restrict__ q,
                                                float* __restrict__ k,
                                                float* __restrict__ v)
{
    const float* B;
    float* C;
    if (blockIdx.z == 0)      { B = Wq; C = q; }
    else if (blockIdx.z == 1) { B = Wk; C = k; }
    else                      { B = Wv; C = v; }
    gemm_tile(X, B, C);
}

__global__ __launch_bounds__(256) void gemm_proj(const float* __restrict__ Ain,
                                                 const float* __restrict__ Wproj,
                                                 float* __restrict__ Cout)
{
    gemm_tile(Ain, Wproj, Cout);
}

// ---------------------------------------------------------------------------
// Attention: one block (256 threads) per pixel position.
// Stage q row in LDS; 128 threads compute (head, a) scores; 8 threads do
// bilinear-weighted stable softmax; 256 threads do coalesced P·V.
// ---------------------------------------------------------------------------
__global__ __launch_bounds__(256) void attn_kernel(const float* __restrict__ q,
                                                   const float* __restrict__ k,
                                                   const float* __restrict__ v,
                                                   const float* __restrict__ moff,
                                                   float* __restrict__ out)
{
    const int pos = blockIdx.x;          // 0 .. B*Nn-1
    const int b   = pos / Nn;
    const int t   = threadIdx.x;

    __shared__ float qs[256];
    __shared__ int   idxS[16];
    __shared__ float bwS[16];
    __shared__ float scores[8][16];
    __shared__ float pS[8][16];

    qs[t] = q[(size_t)pos * 256 + t];

    if (t == 0) {
        float ox = moff[(size_t)pos * 2 + 0];
        float oy = moff[(size_t)pos * 2 + 1];
        // clamp so the 4x4 window stays in-bounds (matches reference)
        ox = fminf(fmaxf(ox, 1.0f), (float)(Ww - 2) - 0.001f);  // 157.999
        oy = fminf(fmaxf(oy, 1.0f), (float)(Hh - 2) - 0.001f);  // 61.999
        float mxf = floorf(ox), myf = floorf(oy);
        float fx = ox - mxf, fy = oy - myf;
        int imx = (int)mxf, imy = (int)myf;
        float wxv[4] = {1.0f - fx, 1.0f, 1.0f, fx};
        float wyv[4] = {1.0f - fy, 1.0f, 1.0f, fy};
#pragma unroll
        for (int r = 0; r < 4; ++r) {
#pragma unroll
            for (int c = 0; c < 4; ++c) {
                idxS[r * 4 + c] = (imy + r - 1) * Ww + (imx + c - 1);
                bwS[r * 4 + c]  = wyv[r] * wxv[c];
            }
        }
    }
    __syncthreads();

    if (t < 128) {
        const int h = t >> 4;
        const int a = t & 15;
        const float* krow = k + ((size_t)(b * Nn + idxS[a])) * 256 + h * 32;
        const float* qh   = qs + h * 32;
        float s = 0.0f;
#pragma unroll
        for (int j = 0; j < 32; ++j) s += qh[j] * krow[j];
        scores[h][a] = s * SCALEf;
    }
    __syncthreads();

    if (t < 8) {
        const int h = t;
        float m = -INFINITY;
#pragma unroll
        for (int a = 0; a < 16; ++a) m = fmaxf(m, scores[h][a]);
        float e[16];
        float sum = 0.0f;
#pragma unroll
        for (int a = 0; a < 16; ++a) {
            e[a] = expf(scores[h][a] - m) * bwS[a];
            sum += e[a];
        }
        float inv = 1.0f / sum;
#pragma unroll
        for (int a = 0; a < 16; ++a) pS[h][a] = e[a] * inv;
    }
    __syncthreads();

    {
        const int h = t >> 5;
        float acc = 0.0f;
#pragma unroll
        for (int a = 0; a < 16; ++a) {
            acc += pS[h][a] * v[((size_t)(b * Nn + idxS[a])) * 256 + t];
        }
        out[(size_t)pos * 256 + t] = acc;
    }
}

// ---------------------------------------------------------------------------
extern "C" void kernel_launch(void* const* d_in, const int* in_sizes, int n_in,
                              void* d_out, int out_size, void* d_ws, size_t ws_size,
                              hipStream_t stream)
{
    const float* x     = (const float*)d_in[0];   // (B,H,W,DIM)
    const float* moff  = (const float*)d_in[1];   // (B,H*W,2)
    const float* Wq    = (const float*)d_in[2];   // (256,256)
    const float* Wk    = (const float*)d_in[3];
    const float* Wv    = (const float*)d_in[4];
    const float* Wproj = (const float*)d_in[5];
    float* out = (float*)d_out;

    float* ws = (float*)d_ws;
    const size_t stride = (size_t)Bb * Nn * DIMc;  // 5,242,880 floats = 20 MiB
    float* q  = ws;
    float* k  = ws + stride;
    float* v  = ws + 2 * stride;
    float* ao = ws + 3 * stride;

    const int Mtiles = (Bb * Nn) / 64;  // 320
    const int Ntiles = DIMc / 64;       // 4

    gemm_qkv<<<dim3(Ntiles, Mtiles, 3), dim3(256), 0, stream>>>(x, Wq, Wk, Wv, q, k, v);
    attn_kernel<<<dim3(Bb * Nn), dim3(256), 0, stream>>>(q, k, v, moff, ao);
    gemm_proj<<<dim3(Ntiles, Mtiles, 1), dim3(256), 0, stream>>>(ao, Wproj, out);
}

// Round 2
// 149.694 us; speedup vs baseline: 2.0951x; 2.0951x over previous
//
#include <hip/hip_runtime.h>
#include <math.h>

// Problem constants
#define Bb   2
#define Hh   64
#define Ww   160
#define DIMc 256
#define NHh  8
#define Nn   (Hh * Ww)                 // 10240 positions per batch
#define SCALEf 0.17677669529663687f    // 32^-0.5

typedef unsigned short u16;
typedef unsigned int   u32;
typedef __bf16 bf16x8 __attribute__((ext_vector_type(8)));
typedef float  f32x4  __attribute__((ext_vector_type(4)));

// fp32 -> bf16 round-to-nearest-even
__device__ __forceinline__ u16 f2bf(float f) {
    u32 u = __float_as_uint(f);
    u += 0x7fffu + ((u >> 16) & 1u);
    return (u16)(u >> 16);
}
// packed bf16 pair -> floats (exact)
__device__ __forceinline__ float bflo(u32 u) { return __uint_as_float(u << 16); }
__device__ __forceinline__ float bfhi(u32 u) { return __uint_as_float(u & 0xffff0000u); }

// ---------------------------------------------------------------------------
// Converters
// ---------------------------------------------------------------------------
__global__ __launch_bounds__(256) void convert_x(const float* __restrict__ x,
                                                 u16* __restrict__ xb)
{
    size_t id = (size_t)blockIdx.x * 256 + threadIdx.x;   // one float4 per thread
    float4 vv = *(const float4*)(x + id * 4);
    ushort4 ov = make_ushort4(f2bf(vv.x), f2bf(vv.y), f2bf(vv.z), f2bf(vv.w));
    *(ushort4*)(xb + id * 4) = ov;
}

// Wt[wsel][n][k] = W[wsel][k][n], bf16.  262144 threads total.
__global__ __launch_bounds__(256) void convert_w(const float* __restrict__ Wq,
                                                 const float* __restrict__ Wk,
                                                 const float* __restrict__ Wv,
                                                 const float* __restrict__ Wp,
                                                 u16* __restrict__ WtAll)
{
    int id = blockIdx.x * 256 + threadIdx.x;
    int wsel = id >> 16;
    int rem  = id & 65535;
    int k = rem >> 8, n = rem & 255;
    const float* W = (wsel == 0) ? Wq : (wsel == 1) ? Wk : (wsel == 2) ? Wv : Wp;
    WtAll[(size_t)wsel * 65536 + n * 256 + k] = f2bf(W[k * 256 + n]);
}

// ---------------------------------------------------------------------------
// bf16 MFMA GEMM: C[M x 256] = A[M x 256] @ Bt^T   (Bt is N-major 256x256)
// 128x128 block tile, 256 threads = 4 waves in 2x2, each wave 4x4 grid of
// 16x16x32 MFMAs. BK=32, register-staged LDS (m93 structure).
// ---------------------------------------------------------------------------
template <bool BF16OUT>
__device__ __forceinline__ void gemm_core(const u16* __restrict__ Ag,
                                          const u16* __restrict__ Btg,
                                          u16* __restrict__ Cb,
                                          float* __restrict__ Cf)
{
    __shared__ u16 sA[128 * 32];
    __shared__ u16 sB[128 * 32];

    const int t    = threadIdx.x;
    const int lane = t & 63;
    const int wv   = t >> 6;
    const int wm   = wv & 1;      // wave m-half
    const int wn   = wv >> 1;     // wave n-half
    const int m0   = blockIdx.y * 128;
    const int n0   = blockIdx.x * 128;

    // staging: thread t covers rows r0 and r0+64, 8 bf16 (16B) each
    const int r0  = t >> 2;
    const int kc0 = (t & 3) * 8;

    const int col  = lane & 15;
    const int quad = lane >> 4;

    f32x4 acc[4][4];
#pragma unroll
    for (int i = 0; i < 4; ++i)
#pragma unroll
        for (int j = 0; j < 4; ++j)
            acc[i][j] = (f32x4){0.f, 0.f, 0.f, 0.f};

    const u16* Abase = Ag + (size_t)m0 * 256;
    const u16* Bbase = Btg + (size_t)n0 * 256;

    for (int k0 = 0; k0 < 256; k0 += 32) {
        uint4 a0 = *(const uint4*)(Abase + (size_t)r0 * 256 + k0 + kc0);
        uint4 a1 = *(const uint4*)(Abase + (size_t)(64 + r0) * 256 + k0 + kc0);
        uint4 b0 = *(const uint4*)(Bbase + (size_t)r0 * 256 + k0 + kc0);
        uint4 b1 = *(const uint4*)(Bbase + (size_t)(64 + r0) * 256 + k0 + kc0);
        __syncthreads();
        *(uint4*)(sA + r0 * 32 + kc0)        = a0;
        *(uint4*)(sA + (64 + r0) * 32 + kc0) = a1;
        *(uint4*)(sB + r0 * 32 + kc0)        = b0;
        *(uint4*)(sB + (64 + r0) * 32 + kc0) = b1;
        __syncthreads();

        bf16x8 af[4], bfr[4];
#pragma unroll
        for (int mt = 0; mt < 4; ++mt)
            af[mt] = *(const bf16x8*)(sA + (wm * 64 + mt * 16 + col) * 32 + quad * 8);
#pragma unroll
        for (int nt = 0; nt < 4; ++nt)
            bfr[nt] = *(const bf16x8*)(sB + (wn * 64 + nt * 16 + col) * 32 + quad * 8);

#pragma unroll
        for (int mt = 0; mt < 4; ++mt)
#pragma unroll
            for (int nt = 0; nt < 4; ++nt)
                acc[mt][nt] = __builtin_amdgcn_mfma_f32_16x16x32_bf16(af[mt], bfr[nt], acc[mt][nt], 0, 0, 0);
    }

    // epilogue: C/D layout col=lane&15, row=quad*4+reg  (m89-verified)
#pragma unroll
    for (int mt = 0; mt < 4; ++mt) {
#pragma unroll
        for (int nt = 0; nt < 4; ++nt) {
            const int rowb = m0 + wm * 64 + mt * 16 + quad * 4;
            const int colg = n0 + wn * 64 + nt * 16 + col;
#pragma unroll
            for (int rr = 0; rr < 4; ++rr) {
                float val = acc[mt][nt][rr];
                if (BF16OUT) Cb[(size_t)(rowb + rr) * 256 + colg] = f2bf(val);
                else         Cf[(size_t)(rowb + rr) * 256 + colg] = val;
            }
        }
    }
}

__global__ __launch_bounds__(256) void gemm_qkv(const u16* __restrict__ xb,
                                                const u16* __restrict__ WtAll,
                                                u16* __restrict__ q,
                                                u16* __restrict__ k,
                                                u16* __restrict__ v)
{
    const int z = blockIdx.z;
    u16* C = (z == 0) ? q : (z == 1) ? k : v;
    gemm_core<true>(xb, WtAll + (size_t)z * 65536, C, nullptr);
}

__global__ __launch_bounds__(256) void gemm_proj(const u16* __restrict__ ao,
                                                 const u16* __restrict__ WtAll,
                                                 float* __restrict__ out)
{
    gemm_core<false>(ao, WtAll + (size_t)3 * 65536, nullptr, out);
}

// ---------------------------------------------------------------------------
// Attention: one 128-thread block per pixel, bf16 q/k/v, fp32 math,
// bf16 attn_out (feeds proj MFMA).
// ---------------------------------------------------------------------------
__global__ __launch_bounds__(128) void attn_kernel(const u16* __restrict__ q,
                                                   const u16* __restrict__ k,
                                                   const u16* __restrict__ v,
                                                   const float* __restrict__ moff,
                                                   u16* __restrict__ out)
{
    const int pos  = blockIdx.x;
    const int t    = threadIdx.x;
    const int brow = (pos >= Nn) ? Nn : 0;   // batch base row

    __shared__ float qs[256];
    __shared__ int   idxS[16];
    __shared__ float bwS[16];
    __shared__ float scores[8][16];
    __shared__ float pS[8][16];

    // stage q row as floats
    u32 qw = *(const u32*)(q + (size_t)pos * 256 + 2 * t);
    qs[2 * t]     = bflo(qw);
    qs[2 * t + 1] = bfhi(qw);

    if (t == 0) {
        float ox = moff[(size_t)pos * 2 + 0];
        float oy = moff[(size_t)pos * 2 + 1];
        ox = fminf(fmaxf(ox, 1.0f), (float)(Ww - 2) - 0.001f);  // 157.999
        oy = fminf(fmaxf(oy, 1.0f), (float)(Hh - 2) - 0.001f);  // 61.999
        float mxf = floorf(ox), myf = floorf(oy);
        float fx = ox - mxf, fy = oy - myf;
        int imx = (int)mxf, imy = (int)myf;
        float wxv[4] = {1.0f - fx, 1.0f, 1.0f, fx};
        float wyv[4] = {1.0f - fy, 1.0f, 1.0f, fy};
#pragma unroll
        for (int r = 0; r < 4; ++r)
#pragma unroll
            for (int c = 0; c < 4; ++c) {
                idxS[r * 4 + c] = (imy + r - 1) * Ww + (imx + c - 1);
                bwS[r * 4 + c]  = wyv[r] * wxv[c];
            }
    }
    __syncthreads();

    // scores: 128 threads = 8 heads x 16 window elems
    {
        const int h = t >> 4, a = t & 15;
        const uint4* kp = (const uint4*)(k + ((size_t)(brow + idxS[a])) * 256 + h * 32);
        float s = 0.f;
#pragma unroll
        for (int jj = 0; jj < 4; ++jj) {
            uint4 w4 = kp[jj];
            const float* qh = qs + h * 32 + jj * 8;
            s += qh[0] * bflo(w4.x) + qh[1] * bfhi(w4.x)
               + qh[2] * bflo(w4.y) + qh[3] * bfhi(w4.y)
               + qh[4] * bflo(w4.z) + qh[5] * bfhi(w4.z)
               + qh[6] * bflo(w4.w) + qh[7] * bfhi(w4.w);
        }
        scores[h][a] = s * SCALEf;
    }
    __syncthreads();

    // bilinear-weighted stable softmax, one thread per head
    if (t < 8) {
        float m = -INFINITY;
#pragma unroll
        for (int a = 0; a < 16; ++a) m = fmaxf(m, scores[t][a]);
        float e[16];
        float sum = 0.f;
#pragma unroll
        for (int a = 0; a < 16; ++a) {
            e[a] = expf(scores[t][a] - m) * bwS[a];
            sum += e[a];
        }
        float inv = 1.0f / sum;
#pragma unroll
        for (int a = 0; a < 16; ++a) pS[t][a] = e[a] * inv;
    }
    __syncthreads();

    // P·V: thread t handles channel pair (2t, 2t+1)
    {
        const int h = t >> 4;
        float acc0 = 0.f, acc1 = 0.f;
#pragma unroll
        for (int a = 0; a < 16; ++a) {
            u32 w2 = *(const u32*)(v + ((size_t)(brow + idxS[a])) * 256 + 2 * t);
            float p = pS[h][a];
            acc0 += p * bflo(w2);
            acc1 += p * bfhi(w2);
        }
        u32 packed = ((u32)f2bf(acc1) << 16) | (u32)f2bf(acc0);
        *(u32*)(out + (size_t)pos * 256 + 2 * t) = packed;
    }
}

// ---------------------------------------------------------------------------
extern "C" void kernel_launch(void* const* d_in, const int* in_sizes, int n_in,
                              void* d_out, int out_size, void* d_ws, size_t ws_size,
                              hipStream_t stream)
{
    const float* x     = (const float*)d_in[0];
    const float* moff  = (const float*)d_in[1];
    const float* Wq    = (const float*)d_in[2];
    const float* Wk    = (const float*)d_in[3];
    const float* Wv    = (const float*)d_in[4];
    const float* Wproj = (const float*)d_in[5];
    float* out = (float*)d_out;

    const size_t NTOT = (size_t)Bb * Nn * DIMc;   // 5,242,880
    u16* ws    = (u16*)d_ws;
    u16* xb    = ws;                     // bf16 x
    u16* WtAll = xb + NTOT;              // 4 transposed bf16 weights
    u16* q     = WtAll + 4 * 65536;
    u16* k     = q + NTOT;
    u16* v     = k + NTOT;
    u16* ao    = v + NTOT;               // bf16 attn output

    convert_x<<<dim3((int)(NTOT / 4 / 256)), dim3(256), 0, stream>>>(x, xb);
    convert_w<<<dim3(1024), dim3(256), 0, stream>>>(Wq, Wk, Wv, Wproj, WtAll);
    gemm_qkv<<<dim3(2, 160, 3), dim3(256), 0, stream>>>(xb, WtAll, q, k, v);
    attn_kernel<<<dim3(Bb * Nn), dim3(128), 0, stream>>>(q, k, v, moff, ao);
    gemm_proj<<<dim3(2, 160, 1), dim3(256), 0, stream>>>(ao, WtAll, out);
}